// Round 1
// baseline (1966.323 us; speedup 1.0000x reference)
//
#include <hip/hip_runtime.h>
#include <math.h>

#define NN 4096
#define NCOEF 7

typedef float4 f4;

// ---------------- degree: deg_inv[j] = 1/(sum_i adj[i,j] + 1e-6) ----------------
__global__ void colsum_part(const float* __restrict__ adj, float* __restrict__ part) {
  int j = blockIdx.x * 256 + threadIdx.x;
  int i0 = blockIdx.y * 256;
  float s = 0.f;
  #pragma unroll 4
  for (int i = 0; i < 256; ++i) s += adj[(size_t)(i0 + i) * NN + j];
  part[(size_t)blockIdx.y * NN + j] = s;
}

__global__ void colsum_fin(const float* __restrict__ part, float* __restrict__ deg_inv) {
  int j = blockIdx.x * 256 + threadIdx.x;
  float s = 0.f;
  #pragma unroll
  for (int k = 0; k < 16; ++k) s += part[(size_t)k * NN + j];
  deg_inv[j] = 1.0f / (s + 1e-6f);
}

// ---------------- MultiConv1D (K=1,3,5,7), 'SAME', x[N,64] -> ybcn[256,N] ----------------
__global__ void multiconv(const float* __restrict__ x,
                          const float* __restrict__ w0, const float* __restrict__ b0,
                          const float* __restrict__ w1, const float* __restrict__ b1,
                          const float* __restrict__ w2, const float* __restrict__ b2,
                          const float* __restrict__ w3, const float* __restrict__ b3,
                          float* __restrict__ ybcn) {
  __shared__ float xs[22][64];
  const int nb = blockIdx.x * 16;
  const int t = threadIdx.x;
  for (int e = t; e < 22 * 64; e += 256) {
    int r = e >> 6, f = e & 63;
    int n = nb - 3 + r;
    xs[r][f] = (n >= 0 && n < NN) ? x[(size_t)n * 64 + f] : 0.f;
  }
  __syncthreads();
  const int br = t >> 6, o = t & 63;
  const float* Wp; const float* Bp; int K;
  if (br == 0)      { Wp = w0; Bp = b0; K = 1; }
  else if (br == 1) { Wp = w1; Bp = b1; K = 3; }
  else if (br == 2) { Wp = w2; Bp = b2; K = 5; }
  else              { Wp = w3; Bp = b3; K = 7; }
  const int off = K >> 1;
  float acc[16];
  float bias = Bp[o];
  #pragma unroll
  for (int j = 0; j < 16; ++j) acc[j] = bias;
  for (int c = 0; c < 64; ++c) {
    for (int k = 0; k < K; ++k) {
      float w = Wp[(o * 64 + c) * K + k];
      int base = 3 - off + k;
      #pragma unroll
      for (int j = 0; j < 16; ++j) acc[j] += xs[base + j][c] * w;
    }
  }
  for (int j = 0; j < 16; ++j) ybcn[(size_t)t * NN + nb + j] = acc[j];
}

// ---------------- generic out[128,N] = W[128,C_] @ in[C_,N] + bias (+extra) ----------------
__global__ __launch_bounds__(256)
void matmul128(const float* __restrict__ W, const float* __restrict__ bias,
               const float* __restrict__ in, int C_,
               const float* __restrict__ extra, float* __restrict__ out) {
  __shared__ float ins[32][68];
  __shared__ float wl[128][33];
  const int nb = blockIdx.x * 64;
  const int t = threadIdx.x;
  const int tn = t & 15, tg = t >> 4;   // n offset tn*4, o base tg*8
  float acc[8][4];
  #pragma unroll
  for (int r = 0; r < 8; ++r)
    #pragma unroll
    for (int c = 0; c < 4; ++c) acc[r][c] = 0.f;

  for (int ct = 0; ct < C_; ct += 32) {
    __syncthreads();
    #pragma unroll
    for (int r = 0; r < 8; ++r) {
      int e = r * 256 + t; int cc = e >> 6, n = e & 63;
      ins[cc][n] = in[(size_t)(ct + cc) * NN + nb + n];
    }
    #pragma unroll
    for (int r = 0; r < 16; ++r) {
      int e = r * 256 + t; int oo = e >> 5, cc = e & 31;
      wl[oo][cc] = W[(size_t)oo * C_ + ct + cc];
    }
    __syncthreads();
    for (int cc = 0; cc < 32; ++cc) {
      f4 iv = *(const f4*)&ins[cc][tn * 4];
      #pragma unroll
      for (int r = 0; r < 8; ++r) {
        float w = wl[tg * 8 + r][cc];
        acc[r][0] += w * iv.x; acc[r][1] += w * iv.y;
        acc[r][2] += w * iv.z; acc[r][3] += w * iv.w;
      }
    }
  }
  #pragma unroll
  for (int r = 0; r < 8; ++r) {
    int o = tg * 8 + r;
    float b = bias[o];
    size_t idx = (size_t)o * NN + nb + tn * 4;
    f4 v;
    v.x = acc[r][0] + b; v.y = acc[r][1] + b; v.z = acc[r][2] + b; v.w = acc[r][3] + b;
    if (extra) {
      f4 e4 = *(const f4*)&extra[idx];
      v.x += e4.x; v.y += e4.y; v.z += e4.z; v.w += e4.w;
    }
    *(f4*)&out[idx] = v;
  }
}

// ---------------- row scale: us[j,f] = u[j,f] * deg_inv[j] ----------------
__global__ void scale_rows(const float* __restrict__ u, const float* __restrict__ deg_inv,
                           float* __restrict__ us, int F) {
  size_t id = (size_t)blockIdx.x * 256 + threadIdx.x;  // float4 index
  int per_row = F >> 2;
  size_t tot = (size_t)NN * per_row;
  if (id >= tot) return;
  f4 v = ((const f4*)u)[id];
  float s = deg_inv[id / per_row];
  v.x *= s; v.y *= s; v.z *= s; v.w *= s;
  ((f4*)us)[id] = v;
}

// ---------------- split-K GEMM: part[z][i,f] = sum_{j in chunk z} adj[i,j]*rhs[j,f] ----------------
template<int FCOLS, int KSPLIT>
__global__ __launch_bounds__(256)
void adjgemm(const float* __restrict__ adj, const float* __restrict__ rhs,
             float* __restrict__ part) {
  constexpr int FT = FCOLS / 16;        // 4 or 8 cols per thread
  constexpr int KLEN = NN / KSPLIT;
  const int ib = blockIdx.x * 64;
  const int j0 = blockIdx.z * KLEN;
  const int t = threadIdx.x;
  const int tf = t & 15, ti = t >> 4;
  __shared__ __align__(16) float rs[32][FCOLS + 4];
  float acc[4][FT];
  #pragma unroll
  for (int r = 0; r < 4; ++r)
    #pragma unroll
    for (int c = 0; c < FT; ++c) acc[r][c] = 0.f;

  const float* ap[4];
  #pragma unroll
  for (int r = 0; r < 4; ++r) ap[r] = adj + (size_t)(ib + ti * 4 + r) * NN + j0;

  for (int jt = 0; jt < KLEN; jt += 32) {
    __syncthreads();
    #pragma unroll
    for (int r = 0; r < (32 * FCOLS) / 256; ++r) {
      int e = r * 256 + t;
      int jj = e / FCOLS, ff = e % FCOLS;
      rs[jj][ff] = rhs[(size_t)(j0 + jt + jj) * FCOLS + ff];
    }
    __syncthreads();
    #pragma unroll
    for (int q = 0; q < 8; ++q) {
      float av[4][4];
      #pragma unroll
      for (int r = 0; r < 4; ++r) {
        f4 a = *(const f4*)(ap[r] + jt + q * 4);
        av[r][0] = a.x; av[r][1] = a.y; av[r][2] = a.z; av[r][3] = a.w;
      }
      #pragma unroll
      for (int p = 0; p < 4; ++p) {
        float bv[FT];
        #pragma unroll
        for (int c4 = 0; c4 < FT / 4; ++c4) {
          f4 b = *(const f4*)&rs[q * 4 + p][tf * FT + c4 * 4];
          bv[c4 * 4 + 0] = b.x; bv[c4 * 4 + 1] = b.y;
          bv[c4 * 4 + 2] = b.z; bv[c4 * 4 + 3] = b.w;
        }
        #pragma unroll
        for (int r = 0; r < 4; ++r)
          #pragma unroll
          for (int c = 0; c < FT; ++c) acc[r][c] += av[r][p] * bv[c];
      }
    }
  }
  float* pp = part + (size_t)blockIdx.z * ((size_t)NN * FCOLS);
  #pragma unroll
  for (int r = 0; r < 4; ++r) {
    #pragma unroll
    for (int c4 = 0; c4 < FT / 4; ++c4) {
      f4 v;
      v.x = acc[r][c4 * 4 + 0]; v.y = acc[r][c4 * 4 + 1];
      v.z = acc[r][c4 * 4 + 2]; v.w = acc[r][c4 * 4 + 3];
      *(f4*)&pp[(size_t)(ib + ti * 4 + r) * FCOLS + tf * FT + c4 * 4] = v;
    }
  }
}

// ---------------- reduce split-K + P epilogue: out = 0.5*(u + sum); us = out*deg_inv ----------------
__global__ void reduce_P(const float* __restrict__ part, const float* __restrict__ u,
                         float* __restrict__ outp, float* __restrict__ usp,
                         const float* __restrict__ deg_inv, int F, int ksplit) {
  size_t id = (size_t)blockIdx.x * 256 + threadIdx.x;  // float4 index
  int per_row = F >> 2;
  size_t tot = (size_t)NN * per_row;
  if (id >= tot) return;
  f4 s = make_float4(0.f, 0.f, 0.f, 0.f);
  for (int k = 0; k < ksplit; ++k) {
    f4 p = ((const f4*)part)[(size_t)k * tot + id];
    s.x += p.x; s.y += p.y; s.z += p.z; s.w += p.w;
  }
  f4 uu = ((const f4*)u)[id];
  f4 o;
  o.x = 0.5f * (uu.x + s.x); o.y = 0.5f * (uu.y + s.y);
  o.z = 0.5f * (uu.z + s.z); o.w = 0.5f * (uu.w + s.w);
  ((f4*)outp)[id] = o;
  if (usp) {
    float sc = deg_inv[id / per_row];
    o.x *= sc; o.y *= sc; o.z *= sc; o.w *= sc;
    ((f4*)usp)[id] = o;
  }
}

// ---------------- reduce split-K + transpose: agg[c,i] = sum_k part[k][i,c] (F=128) ----------------
__global__ void reduce_T(const float* __restrict__ part, float* __restrict__ outT, int ksplit) {
  __shared__ float T[64][65];
  const int ib = blockIdx.x * 64, cb = blockIdx.y * 64;
  const int t = threadIdx.x;
  #pragma unroll
  for (int r = 0; r < 16; ++r) {
    int e = r * 256 + t; int il = e >> 6, c = e & 63;
    float s = 0.f;
    for (int k = 0; k < ksplit; ++k)
      s += part[(size_t)k * NN * 128 + (size_t)(ib + il) * 128 + cb + c];
    T[il][c] = s;
  }
  __syncthreads();
  #pragma unroll
  for (int r = 0; r < 16; ++r) {
    int e = r * 256 + t; int c = e >> 6, il = e & 63;
    outT[(size_t)(cb + c) * NN + ib + il] = T[il][c];
  }
}

// ---------------- scatter |A-B| (or A) into gst[(f*7+coef)*NN + n], optional copy into cat ----------------
__global__ void scatter_coef(const float* __restrict__ A, const float* __restrict__ B,
                             int strideA, int offA, float* __restrict__ gst, int coef,
                             float* __restrict__ cat, int catoff) {
  __shared__ float T[64][65];
  const int nb = blockIdx.x * 64;
  const int t = threadIdx.x;
  #pragma unroll
  for (int r = 0; r < 16; ++r) {
    int e = r * 256 + t; int nl = e >> 6, f = e & 63;
    size_t idx = (size_t)(nb + nl) * strideA + offA + f;
    float v = A[idx];
    if (B) v = fabsf(v - B[idx]);
    T[nl][f] = v;
  }
  __syncthreads();
  #pragma unroll
  for (int r = 0; r < 16; ++r) {
    int e = r * 256 + t; int f = e >> 6, nl = e & 63;
    gst[(size_t)(f * NCOEF + coef) * NN + nb + nl] = T[nl][f];
  }
  if (cat) {
    #pragma unroll
    for (int r = 0; r < 16; ++r) {
      int e = r * 256 + t; int nl = e >> 6, f = e & 63;
      cat[(size_t)(nb + nl) * 128 + catoff + f] = T[nl][f];
    }
  }
}

// ---------------- transpose x4[128,N] -> xfT[N,128] ----------------
__global__ void transpose128(const float* __restrict__ x4, float* __restrict__ xfT) {
  __shared__ float T[64][65];
  const int nb = blockIdx.x * 64, cb = blockIdx.y * 64;
  const int t = threadIdx.x;
  #pragma unroll
  for (int r = 0; r < 16; ++r) {
    int e = r * 256 + t; int c = e >> 6, nl = e & 63;
    T[c][nl] = x4[(size_t)(cb + c) * NN + nb + nl];
  }
  __syncthreads();
  #pragma unroll
  for (int r = 0; r < 16; ++r) {
    int e = r * 256 + t; int nl = e >> 6, c = e & 63;
    xfT[(size_t)(nb + nl) * 128 + cb + c] = T[c][nl];
  }
}

// ---------------- oscillator unit-norm init: x4 = x0 / (||x0||_osc + 1e-6) ----------------
__global__ void norm_init(const float* __restrict__ x0, float* __restrict__ x4) {
  int n = blockIdx.x * 256 + threadIdx.x;
  int g = blockIdx.y;
  float v[4]; float ss = 0.f;
  #pragma unroll
  for (int o = 0; o < 4; ++o) { v[o] = x0[(size_t)(g * 4 + o) * NN + n]; ss += v[o] * v[o]; }
  float inv = 1.f / (sqrtf(ss) + 1e-6f);
  #pragma unroll
  for (int o = 0; o < 4; ++o) x4[(size_t)(g * 4 + o) * NN + n] = v[o] * inv;
}

// ---------------- GroupNorm stats per group (32 groups over 4*NN elems) ----------------
__global__ void gn_stats(const float* __restrict__ c, float* __restrict__ stat) {
  const int g = blockIdx.x;
  const int t = threadIdx.x;
  const float* base = c + (size_t)g * 4 * NN;
  float s = 0.f, ss = 0.f;
  for (int e = t; e < 4 * NN; e += 256) { float v = base[e]; s += v; ss += v * v; }
  #pragma unroll
  for (int off = 32; off > 0; off >>= 1) { s += __shfl_down(s, off); ss += __shfl_down(ss, off); }
  __shared__ float rs[4], rss[4];
  if ((t & 63) == 0) { rs[t >> 6] = s; rss[t >> 6] = ss; }
  __syncthreads();
  if (t == 0) {
    float S = rs[0] + rs[1] + rs[2] + rs[3];
    float SS = rss[0] + rss[1] + rss[2] + rss[3];
    float mu = S / (4.f * NN);
    float var = SS / (4.f * NN) - mu * mu;
    stat[g * 2] = mu;
    stat[g * 2 + 1] = rsqrtf(var + 1e-5f);
  }
}

// ---------------- Kuramoto step: GN + tangent projection + renorm ----------------
__global__ void kur_update(const float* __restrict__ cb, const float* __restrict__ stat,
                           const float* __restrict__ gng, const float* __restrict__ gnb,
                           float* __restrict__ x4) {
  int n = blockIdx.x * 256 + threadIdx.x;
  int g = blockIdx.y;
  float mu = stat[g * 2], rstd = stat[g * 2 + 1];
  float cn[4], xo[4];
  float inner = 0.f;
  #pragma unroll
  for (int o = 0; o < 4; ++o) {
    size_t idx = (size_t)(g * 4 + o) * NN + n;
    float cv = (cb[idx] - mu) * rstd * gng[g * 4 + o] + gnb[g * 4 + o];
    float xv = x4[idx];
    cn[o] = cv; xo[o] = xv; inner += cv * xv;
  }
  float ssq = 0.f;
  #pragma unroll
  for (int o = 0; o < 4; ++o) {
    float xn = xo[o] + (cn[o] - inner * xo[o]);   // gamma = 1
    cn[o] = xn; ssq += xn * xn;
  }
  float inv = 1.f / (sqrtf(ssq) + 1e-6f);
  #pragma unroll
  for (int o = 0; o < 4; ++o) x4[(size_t)(g * 4 + o) * NN + n] = cn[o] * inv;
}

// ---------------- rotor magnitude: mag[g,n] = sqrt(sum_o v^2 + 1e-6) ----------------
__global__ void mag_kernel(const float* __restrict__ v, float* __restrict__ mag) {
  int n = blockIdx.x * 256 + threadIdx.x;
  int g = blockIdx.y;
  float ss = 0.f;
  #pragma unroll
  for (int o = 0; o < 4; ++o) {
    float x = v[(size_t)(g * 4 + o) * NN + n];
    ss += x * x;
  }
  mag[(size_t)g * NN + n] = sqrtf(ss + 1e-6f);
}

// ---------------- head: logits[n,k] = sum_o xs[o,n]*out_w[k,o] + out_b[k] ----------------
__global__ void head(const float* __restrict__ xs, const float* __restrict__ ow,
                     const float* __restrict__ ob, float* __restrict__ out) {
  __shared__ float w[512];
  const int t = threadIdx.x;
  for (int e = t; e < 512; e += 256) w[e] = ow[e];
  __syncthreads();
  int n = blockIdx.x * 256 + t;
  float a0 = ob[0], a1 = ob[1], a2 = ob[2], a3 = ob[3];
  for (int o = 0; o < 128; ++o) {
    float v = xs[(size_t)o * NN + n];
    a0 += w[o] * v; a1 += w[128 + o] * v; a2 += w[256 + o] * v; a3 += w[384 + o] * v;
  }
  f4 r; r.x = a0; r.y = a1; r.z = a2; r.w = a3;
  ((f4*)out)[n] = r;
}

extern "C" void kernel_launch(void* const* d_in, const int* in_sizes, int n_in,
                              void* d_out, int out_size, void* d_ws, size_t ws_size,
                              hipStream_t stream) {
  const float* x      = (const float*)d_in[0];
  const float* adj    = (const float*)d_in[1];
  const float* mc_w0  = (const float*)d_in[2];
  const float* mc_b0  = (const float*)d_in[3];
  const float* mc_w1  = (const float*)d_in[4];
  const float* mc_b1  = (const float*)d_in[5];
  const float* mc_w2  = (const float*)d_in[6];
  const float* mc_b2  = (const float*)d_in[7];
  const float* mc_w3  = (const float*)d_in[8];
  const float* mc_b3  = (const float*)d_in[9];
  const float* proj_w = (const float*)d_in[10];
  const float* proj_b = (const float*)d_in[11];
  const float* pat_w  = (const float*)d_in[12];
  const float* pat_b  = (const float*)d_in[13];
  const float* kur_wc = (const float*)d_in[14];
  const float* kur_bc = (const float*)d_in[15];
  const float* kur_wy = (const float*)d_in[16];
  const float* kur_by = (const float*)d_in[17];
  const float* gn_g   = (const float*)d_in[18];
  const float* gn_b   = (const float*)d_in[19];
  const float* ro_w1  = (const float*)d_in[20];
  const float* ro_b1  = (const float*)d_in[21];
  const float* ro_w2  = (const float*)d_in[22];
  const float* ro_b2  = (const float*)d_in[23];
  const float* out_w  = (const float*)d_in[24];
  const float* out_b  = (const float*)d_in[25];
  float* out = (float*)d_out;
  float* W = (float*)d_ws;

  // ---- workspace layout (floats), ~43 MB total ----
  float* deg   = W;                      // 4096
  float* part  = deg + 4096;             // 2,097,152 (8 MB; also colsum partials)
  float* us    = part + 2097152;         // 524,288 (scaled rhs; reused as x_state at end)
  float* A1    = us + 524288;            // 262,144
  float* A2    = A1 + 262144;
  float* A3    = A2 + 262144;
  float* A4    = A3 + 262144;
  float* s1cat = A4 + 262144;            // 524,288  [N,128]
  float* gstf  = s1cat + 524288;         // 1,835,008 [448,N]
  float* ybcn  = gstf + 1835008;         // 1,048,576 [256,N]; reused: B1,B2
  float* B1    = ybcn;
  float* B2    = ybcn + 524288;
  float* ybuf  = ybcn + 1048576;         // 524,288 (y; reused as x0)
  float* x0    = ybuf;
  float* cy    = ybuf + 524288;          // 524,288
  float* B4    = cy + 524288;            // 524,288
  float* x4    = B4 + 524288;            // 524,288
  float* xfT   = x4 + 524288;            // 524,288
  float* agg   = xfT + 524288;           // 524,288 (reused as mag)
  float* magb  = agg;
  float* cbuf  = agg + 524288;           // 524,288 (reused as v)
  float* vbuf  = cbuf;
  float* gnst  = cbuf + 524288;          // 64
  float* xst   = us;

  dim3 b256(256);

  // 1. degree
  colsum_part<<<dim3(16, 16), b256, 0, stream>>>(adj, part);
  colsum_fin<<<dim3(16), b256, 0, stream>>>(part, deg);

  // 2. control pattern y and control term cy
  multiconv<<<dim3(256), b256, 0, stream>>>(x, mc_w0, mc_b0, mc_w1, mc_b1,
                                            mc_w2, mc_b2, mc_w3, mc_b3, ybcn);
  matmul128<<<dim3(64), b256, 0, stream>>>(proj_w, proj_b, ybcn, 256, nullptr, ybuf);
  matmul128<<<dim3(64), b256, 0, stream>>>(kur_wy, kur_by, ybuf, 128, nullptr, cy);

  // 3. GST first order: a1..a4 = P-chain on x
  scale_rows<<<dim3(256), b256, 0, stream>>>(x, deg, us, 64);
  adjgemm<64, 8><<<dim3(64, 1, 8), b256, 0, stream>>>(adj, us, part);
  reduce_P<<<dim3(256), b256, 0, stream>>>(part, x, A1, us, deg, 64, 8);
  adjgemm<64, 8><<<dim3(64, 1, 8), b256, 0, stream>>>(adj, us, part);
  reduce_P<<<dim3(256), b256, 0, stream>>>(part, A1, A2, us, deg, 64, 8);
  adjgemm<64, 8><<<dim3(64, 1, 8), b256, 0, stream>>>(adj, us, part);
  reduce_P<<<dim3(256), b256, 0, stream>>>(part, A2, A3, us, deg, 64, 8);
  adjgemm<64, 8><<<dim3(64, 1, 8), b256, 0, stream>>>(adj, us, part);
  reduce_P<<<dim3(256), b256, 0, stream>>>(part, A3, A4, nullptr, deg, 64, 8);

  scatter_coef<<<dim3(64), b256, 0, stream>>>(x, nullptr, 64, 0, gstf, 0, nullptr, 0);
  scatter_coef<<<dim3(64), b256, 0, stream>>>(x, A1, 64, 0, gstf, 1, s1cat, 0);
  scatter_coef<<<dim3(64), b256, 0, stream>>>(A1, A2, 64, 0, gstf, 2, s1cat, 64);
  scatter_coef<<<dim3(64), b256, 0, stream>>>(A2, A4, 64, 0, gstf, 3, nullptr, 0);

  // 4. GST second order, batched over [s1_0 | s1_1] (128 cols)
  scale_rows<<<dim3(512), b256, 0, stream>>>(s1cat, deg, us, 128);
  adjgemm<128, 4><<<dim3(64, 1, 4), b256, 0, stream>>>(adj, us, part);
  reduce_P<<<dim3(512), b256, 0, stream>>>(part, s1cat, B1, us, deg, 128, 4);
  adjgemm<128, 4><<<dim3(64, 1, 4), b256, 0, stream>>>(adj, us, part);
  reduce_P<<<dim3(512), b256, 0, stream>>>(part, B1, B2, us, deg, 128, 4);
  scatter_coef<<<dim3(64), b256, 0, stream>>>(B1, B2, 128, 0, gstf, 4, nullptr, 0);
  adjgemm<128, 4><<<dim3(64, 1, 4), b256, 0, stream>>>(adj, us, part);
  reduce_P<<<dim3(512), b256, 0, stream>>>(part, B2, B1, us, deg, 128, 4);     // B3 -> B1
  adjgemm<128, 4><<<dim3(64, 1, 4), b256, 0, stream>>>(adj, us, part);
  reduce_P<<<dim3(512), b256, 0, stream>>>(part, B1, B4, nullptr, deg, 128, 4); // B4
  scatter_coef<<<dim3(64), b256, 0, stream>>>(B2, B4, 128, 0, gstf, 5, nullptr, 0);
  scatter_coef<<<dim3(64), b256, 0, stream>>>(B2, B4, 128, 64, gstf, 6, nullptr, 0);

  // 5. x0 = pat_w @ gst_flat + pat_b; oscillator init
  matmul128<<<dim3(64), b256, 0, stream>>>(pat_w, pat_b, gstf, 448, nullptr, x0);
  norm_init<<<dim3(16, 32), b256, 0, stream>>>(x0, x4);

  // 6. Kuramoto dynamics
  for (int q = 0; q < 8; ++q) {
    transpose128<<<dim3(64, 2), b256, 0, stream>>>(x4, xfT);
    adjgemm<128, 4><<<dim3(64, 1, 4), b256, 0, stream>>>(adj, xfT, part);
    reduce_T<<<dim3(64, 2), b256, 0, stream>>>(part, agg, 4);
    matmul128<<<dim3(64), b256, 0, stream>>>(kur_wc, kur_bc, agg, 128, cy, cbuf);
    gn_stats<<<dim3(32), b256, 0, stream>>>(cbuf, gnst);
    kur_update<<<dim3(16, 32), b256, 0, stream>>>(cbuf, gnst, gn_g, gn_b, x4);
  }

  // 7. readout + head
  matmul128<<<dim3(64), b256, 0, stream>>>(ro_w1, ro_b1, x4, 128, nullptr, vbuf);
  mag_kernel<<<dim3(16, 32), b256, 0, stream>>>(vbuf, magb);
  matmul128<<<dim3(64), b256, 0, stream>>>(ro_w2, ro_b2, magb, 32, nullptr, xst);
  head<<<dim3(16), b256, 0, stream>>>(xst, out_w, out_b, out);
}

// Round 2
// 1118.604 us; speedup vs baseline: 1.7578x; 1.7578x over previous
//
#include <hip/hip_runtime.h>
#include <math.h>

#define NN 4096

typedef float4 f4;
typedef _Float16 f16;
typedef _Float16 f16x8 __attribute__((ext_vector_type(8)));
typedef float f32x4v __attribute__((ext_vector_type(4)));

// B-fragment offset (f16 units) for mfma_f32_16x16x32: element (ch=col, n=k).
// Layout: [ktile = n/32][coltile = ch/16] blocks of 512 f16; within block
// lane = (ch&15) + 16*((n&31)/8), elem j = n&7.
__device__ __forceinline__ size_t frag_off(int CT, int ch, int n) {
  return ((size_t)(n >> 5) * CT + (ch >> 4)) * 512
       + (size_t)((((ch & 15) + (((n & 31) >> 3) << 4)) << 3) + (n & 7));
}

// ---------------- adj fp32 -> fp16 A-fragment layout + column-sum partials ----------------
// A-frag for (rowtile rt = i/16, ktile kt = k/32): block at (rt*128+kt)*512,
// lane = (i&15) + 16*((k&31)/8), elem = k&7.
__global__ void convert_cs(const float* __restrict__ adj, f16* __restrict__ adj16,
                           float* __restrict__ csp) {
  const int rb = blockIdx.x;          // 128 blocks of 32 rows
  const int kb = blockIdx.y;          // 2 halves of k
  const int t = threadIdx.x;
  const int k8 = kb * 2048 + t * 8;
  float cs0=0,cs1=0,cs2=0,cs3=0,cs4=0,cs5=0,cs6=0,cs7=0;
  for (int r = 0; r < 32; ++r) {
    const int i = rb * 32 + r;
    const float* src = adj + (size_t)i * NN + k8;
    f4 v0 = *(const f4*)src, v1 = *(const f4*)(src + 4);
    cs0 += v0.x; cs1 += v0.y; cs2 += v0.z; cs3 += v0.w;
    cs4 += v1.x; cs5 += v1.y; cs6 += v1.z; cs7 += v1.w;
    f16x8 fr;
    fr[0]=(f16)v0.x; fr[1]=(f16)v0.y; fr[2]=(f16)v0.z; fr[3]=(f16)v0.w;
    fr[4]=(f16)v1.x; fr[5]=(f16)v1.y; fr[6]=(f16)v1.z; fr[7]=(f16)v1.w;
    size_t off = ((size_t)(i >> 4) * 128 + (k8 >> 5)) * 512
               + (size_t)(((i & 15) + (((k8 & 31) >> 3) << 4)) << 3);
    *(f16x8*)(adj16 + off) = fr;
  }
  float* d = csp + (size_t)rb * NN + k8;
  f4 a; a.x=cs0; a.y=cs1; a.z=cs2; a.w=cs3; *(f4*)d = a;
  f4 b; b.x=cs4; b.y=cs5; b.z=cs6; b.w=cs7; *(f4*)(d+4) = b;
}

__global__ void colsum_fin(const float* __restrict__ csp, float* __restrict__ deg_inv) {
  int j = blockIdx.x * 256 + threadIdx.x;
  float s = 0.f;
  for (int rb = 0; rb < 128; ++rb) s += csp[(size_t)rb * NN + j];
  deg_inv[j] = 1.0f / (s + 1e-6f);
}

// ---------------- MFMA split-K GEMM: part[z][col][node] = sum_j adj[node,j]*rhs_frag[j,col] ----
template<int F, int KZ>
__global__ __launch_bounds__(256)
void adjmm16(const f16* __restrict__ adj16, const f16* __restrict__ rhs,
             float* __restrict__ part) {
  constexpr int CT = F / 16;
  constexpr int NQ = F / 32;
  constexpr int KSTEPS = (NN / KZ) / 32;
  const int t = threadIdx.x;
  const int lane = t & 63;
  const int u = blockIdx.x * 4 + (t >> 6);
  const int nq = u % NQ;
  const int mt = (u / NQ) & 127;            // 128 row groups of 32
  const int kz = u / (NQ * 128);
  const int kt0 = kz * KSTEPS;
  const size_t aoff0 = ((size_t)(mt * 2)     * 128) * 512 + lane * 8;
  const size_t aoff1 = ((size_t)(mt * 2 + 1) * 128) * 512 + lane * 8;
  const size_t boff  = (size_t)(nq * 2) * 512 + lane * 8;
  f32x4v acc00 = {0.f,0.f,0.f,0.f};
  f32x4v acc01 = {0.f,0.f,0.f,0.f};
  f32x4v acc10 = {0.f,0.f,0.f,0.f};
  f32x4v acc11 = {0.f,0.f,0.f,0.f};
  #pragma unroll 4
  for (int i = 0; i < KSTEPS; ++i) {
    const int kt = kt0 + i;
    f16x8 a0 = *(const f16x8*)(adj16 + aoff0 + (size_t)kt * 512);
    f16x8 a1 = *(const f16x8*)(adj16 + aoff1 + (size_t)kt * 512);
    f16x8 b0 = *(const f16x8*)(rhs + (size_t)kt * CT * 512 + boff);
    f16x8 b1 = *(const f16x8*)(rhs + (size_t)kt * CT * 512 + boff + 512);
    acc00 = __builtin_amdgcn_mfma_f32_16x16x32_f16(a0, b0, acc00, 0, 0, 0);
    acc01 = __builtin_amdgcn_mfma_f32_16x16x32_f16(a0, b1, acc01, 0, 0, 0);
    acc10 = __builtin_amdgcn_mfma_f32_16x16x32_f16(a1, b0, acc10, 0, 0, 0);
    acc11 = __builtin_amdgcn_mfma_f32_16x16x32_f16(a1, b1, acc11, 0, 0, 0);
  }
  float* pb = part + (size_t)kz * F * NN;
  const int col0  = nq * 32 + (lane & 15);
  const int node0 = mt * 32 + ((lane >> 4) << 2);
  *(f32x4v*)(pb + (size_t)col0        * NN + node0)      = acc00;
  *(f32x4v*)(pb + (size_t)(col0 + 16) * NN + node0)      = acc01;
  *(f32x4v*)(pb + (size_t)col0        * NN + node0 + 16) = acc10;
  *(f32x4v*)(pb + (size_t)(col0 + 16) * NN + node0 + 16) = acc11;
}

// ---------------- reduce split-K + P epilogue + optional next-rhs frag emission ----------------
__global__ void reduce_P(const float* __restrict__ part, const float* __restrict__ u,
                         float* __restrict__ outp, f16* __restrict__ frag,
                         const float* __restrict__ deg, int F, int KZ) {
  const int id = blockIdx.x * 256 + threadIdx.x;
  const int ch = id >> 9, n0 = (id & 511) << 3;
  const size_t base = (size_t)ch * NN + n0;
  float s[8] = {0,0,0,0,0,0,0,0};
  for (int z = 0; z < KZ; ++z) {
    const float* p = part + (size_t)z * F * NN + base;
    f4 p0 = *(const f4*)p, p1 = *(const f4*)(p + 4);
    s[0]+=p0.x; s[1]+=p0.y; s[2]+=p0.z; s[3]+=p0.w;
    s[4]+=p1.x; s[5]+=p1.y; s[6]+=p1.z; s[7]+=p1.w;
  }
  f4 u0 = *(const f4*)(u + base), u1 = *(const f4*)(u + base + 4);
  float o[8];
  o[0]=0.5f*(u0.x+s[0]); o[1]=0.5f*(u0.y+s[1]); o[2]=0.5f*(u0.z+s[2]); o[3]=0.5f*(u0.w+s[3]);
  o[4]=0.5f*(u1.x+s[4]); o[5]=0.5f*(u1.y+s[5]); o[6]=0.5f*(u1.z+s[6]); o[7]=0.5f*(u1.w+s[7]);
  f4 w0; w0.x=o[0]; w0.y=o[1]; w0.z=o[2]; w0.w=o[3];
  f4 w1; w1.x=o[4]; w1.y=o[5]; w1.z=o[6]; w1.w=o[7];
  *(f4*)(outp + base) = w0; *(f4*)(outp + base + 4) = w1;
  if (frag) {
    f16x8 fr;
    #pragma unroll
    for (int j = 0; j < 8; ++j) fr[j] = (f16)(o[j] * deg[n0 + j]);
    *(f16x8*)(frag + frag_off(F >> 4, ch, n0)) = fr;
  }
}

// ---------------- scatter |A-B| -> gst coef row; optional s1cat copy + frag emission ----------
__global__ void scatter_abs(const float* __restrict__ A, const float* __restrict__ B,
                            float* __restrict__ gbase, float* __restrict__ s1,
                            f16* __restrict__ frag, int chbase,
                            const float* __restrict__ deg) {
  const int id = blockIdx.x * 256 + threadIdx.x;
  const int f = id >> 9, n0 = (id & 511) << 3;
  const size_t base = (size_t)f * NN + n0;
  f4 a0 = *(const f4*)(A + base), a1 = *(const f4*)(A + base + 4);
  f4 b0 = *(const f4*)(B + base), b1 = *(const f4*)(B + base + 4);
  float v[8];
  v[0]=fabsf(a0.x-b0.x); v[1]=fabsf(a0.y-b0.y); v[2]=fabsf(a0.z-b0.z); v[3]=fabsf(a0.w-b0.w);
  v[4]=fabsf(a1.x-b1.x); v[5]=fabsf(a1.y-b1.y); v[6]=fabsf(a1.z-b1.z); v[7]=fabsf(a1.w-b1.w);
  f4 w0; w0.x=v[0]; w0.y=v[1]; w0.z=v[2]; w0.w=v[3];
  f4 w1; w1.x=v[4]; w1.y=v[5]; w1.z=v[6]; w1.w=v[7];
  float* g = gbase + (size_t)f * 7 * NN + n0;
  *(f4*)g = w0; *(f4*)(g + 4) = w1;
  if (s1) { *(f4*)(s1 + base) = w0; *(f4*)(s1 + base + 4) = w1; }
  if (frag) {
    f16x8 fr;
    #pragma unroll
    for (int j = 0; j < 8; ++j) fr[j] = (f16)(v[j] * deg[n0 + j]);
    *(f16x8*)(frag + frag_off(8, chbase + f, n0)) = fr;
  }
}

// ---------------- x[N,64] -> xT[64][N] + gst coef0 + first rhs frag (x*deg_inv) --------------
__global__ void transpose_x(const float* __restrict__ x, const float* __restrict__ deg,
                            float* __restrict__ xT, float* __restrict__ gst,
                            f16* __restrict__ fragA) {
  __shared__ float T[64][65];
  const int nb = blockIdx.x * 64;
  const int t = threadIdx.x;
  #pragma unroll
  for (int r = 0; r < 16; ++r) {
    int e = r * 256 + t; int nl = e >> 6, f = e & 63;
    T[nl][f] = x[(size_t)(nb + nl) * 64 + f];
  }
  __syncthreads();
  #pragma unroll
  for (int r = 0; r < 16; ++r) {
    int e = r * 256 + t; int f = e >> 6, nl = e & 63;
    float v = T[nl][f];
    xT[(size_t)f * NN + nb + nl] = v;
    gst[(size_t)f * 7 * NN + nb + nl] = v;
  }
  #pragma unroll
  for (int k = 0; k < 2; ++k) {
    int fi = k * 256 + t;           // 512 frags: (f, 8-node chunk)
    int f = fi >> 3, n0l = (fi & 7) << 3;
    f16x8 fr;
    #pragma unroll
    for (int j = 0; j < 8; ++j) fr[j] = (f16)(T[n0l + j][f] * deg[nb + n0l + j]);
    *(f16x8*)(fragA + frag_off(4, f, nb + n0l)) = fr;
  }
}

// ---------------- MultiConv1D (K=1,3,5,7), 'SAME', x[N,64] -> ybcn[256,N] ----------------
__global__ void multiconv(const float* __restrict__ x,
                          const float* __restrict__ w0, const float* __restrict__ b0,
                          const float* __restrict__ w1, const float* __restrict__ b1,
                          const float* __restrict__ w2, const float* __restrict__ b2,
                          const float* __restrict__ w3, const float* __restrict__ b3,
                          float* __restrict__ ybcn) {
  __shared__ float xs[22][64];
  const int nb = blockIdx.x * 16;
  const int t = threadIdx.x;
  for (int e = t; e < 22 * 64; e += 256) {
    int r = e >> 6, f = e & 63;
    int n = nb - 3 + r;
    xs[r][f] = (n >= 0 && n < NN) ? x[(size_t)n * 64 + f] : 0.f;
  }
  __syncthreads();
  const int br = t >> 6, o = t & 63;
  const float* Wp; const float* Bp; int K;
  if (br == 0)      { Wp = w0; Bp = b0; K = 1; }
  else if (br == 1) { Wp = w1; Bp = b1; K = 3; }
  else if (br == 2) { Wp = w2; Bp = b2; K = 5; }
  else              { Wp = w3; Bp = b3; K = 7; }
  const int off = K >> 1;
  float acc[16];
  float bias = Bp[o];
  #pragma unroll
  for (int j = 0; j < 16; ++j) acc[j] = bias;
  for (int c = 0; c < 64; ++c) {
    for (int k = 0; k < K; ++k) {
      float w = Wp[(o * 64 + c) * K + k];
      int base = 3 - off + k;
      #pragma unroll
      for (int j = 0; j < 16; ++j) acc[j] += xs[base + j][c] * w;
    }
  }
  for (int j = 0; j < 16; ++j) ybcn[(size_t)t * NN + nb + j] = acc[j];
}

// ---------------- out[128,N] = W[128,C_] @ in[C_,N] + bias (+extra) ; ksplit-sum ; mag ------
__global__ __launch_bounds__(256)
void matmul128(const float* __restrict__ W, const float* __restrict__ bias,
               const float* __restrict__ in, int C_,
               const float* __restrict__ extra, float* __restrict__ out,
               int ksplit, int domag) {
  __shared__ float ins[32][68];
  __shared__ float wl[128][33];
  const int nb = blockIdx.x * 64;
  const int t = threadIdx.x;
  const int tn = t & 15, tg = t >> 4;
  float acc[8][4];
  #pragma unroll
  for (int r = 0; r < 8; ++r)
    #pragma unroll
    for (int c = 0; c < 4; ++c) acc[r][c] = 0.f;

  for (int ct = 0; ct < C_; ct += 32) {
    __syncthreads();
    #pragma unroll
    for (int r = 0; r < 8; ++r) {
      int e = r * 256 + t; int cc = e >> 6, n = e & 63;
      size_t idx = (size_t)(ct + cc) * NN + nb + n;
      float v;
      if (ksplit) {
        v = 0.f;
        for (int z = 0; z < ksplit; ++z) v += in[(size_t)z * 128 * NN + idx];
      } else v = in[idx];
      ins[cc][n] = v;
    }
    #pragma unroll
    for (int r = 0; r < 16; ++r) {
      int e = r * 256 + t; int oo = e >> 5, cc = e & 31;
      wl[oo][cc] = W[(size_t)oo * C_ + ct + cc];
    }
    __syncthreads();
    for (int cc = 0; cc < 32; ++cc) {
      f4 iv = *(const f4*)&ins[cc][tn * 4];
      #pragma unroll
      for (int r = 0; r < 8; ++r) {
        float w = wl[tg * 8 + r][cc];
        acc[r][0] += w * iv.x; acc[r][1] += w * iv.y;
        acc[r][2] += w * iv.z; acc[r][3] += w * iv.w;
      }
    }
  }
  if (domag) {
    #pragma unroll
    for (int h = 0; h < 2; ++h) {
      float m[4];
      #pragma unroll
      for (int c2 = 0; c2 < 4; ++c2) {
        float ss = 1e-6f;
        #pragma unroll
        for (int r = h * 4; r < h * 4 + 4; ++r) {
          float v = acc[r][c2] + bias[tg * 8 + r];
          ss += v * v;
        }
        m[c2] = sqrtf(ss);
      }
      f4 mv; mv.x=m[0]; mv.y=m[1]; mv.z=m[2]; mv.w=m[3];
      *(f4*)&out[(size_t)(tg * 2 + h) * NN + nb + tn * 4] = mv;
    }
    return;
  }
  #pragma unroll
  for (int r = 0; r < 8; ++r) {
    int o = tg * 8 + r;
    float b = bias[o];
    size_t idx = (size_t)o * NN + nb + tn * 4;
    f4 v;
    v.x = acc[r][0] + b; v.y = acc[r][1] + b; v.z = acc[r][2] + b; v.w = acc[r][3] + b;
    if (extra) {
      f4 e4 = *(const f4*)&extra[idx];
      v.x += e4.x; v.y += e4.y; v.z += e4.z; v.w += e4.w;
    }
    *(f4*)&out[idx] = v;
  }
}

// ---------------- oscillator unit-norm init + frag emission ----------------
__global__ void norm_init(const float* __restrict__ x0, float* __restrict__ x4,
                          f16* __restrict__ frag) {
  const int id = blockIdx.x * 256 + threadIdx.x;   // 16384: (g, 8-node chunk)
  const int g = id >> 9, n0 = (id & 511) << 3;
  float v[4][8];
  #pragma unroll
  for (int o = 0; o < 4; ++o) {
    size_t base = (size_t)(g * 4 + o) * NN + n0;
    f4 a = *(const f4*)(x0 + base), b = *(const f4*)(x0 + base + 4);
    v[o][0]=a.x; v[o][1]=a.y; v[o][2]=a.z; v[o][3]=a.w;
    v[o][4]=b.x; v[o][5]=b.y; v[o][6]=b.z; v[o][7]=b.w;
  }
  #pragma unroll
  for (int j = 0; j < 8; ++j) {
    float ss = v[0][j]*v[0][j] + v[1][j]*v[1][j] + v[2][j]*v[2][j] + v[3][j]*v[3][j];
    float inv = 1.f / (sqrtf(ss) + 1e-6f);
    #pragma unroll
    for (int o = 0; o < 4; ++o) v[o][j] *= inv;
  }
  #pragma unroll
  for (int o = 0; o < 4; ++o) {
    size_t base = (size_t)(g * 4 + o) * NN + n0;
    f4 a; a.x=v[o][0]; a.y=v[o][1]; a.z=v[o][2]; a.w=v[o][3];
    f4 b; b.x=v[o][4]; b.y=v[o][5]; b.z=v[o][6]; b.w=v[o][7];
    *(f4*)(x4 + base) = a; *(f4*)(x4 + base + 4) = b;
    f16x8 fr;
    #pragma unroll
    for (int j = 0; j < 8; ++j) fr[j] = (f16)v[o][j];
    *(f16x8*)(frag + frag_off(8, g * 4 + o, n0)) = fr;
  }
}

// ---------------- GroupNorm stats per group ----------------
__global__ void gn_stats(const float* __restrict__ c, float* __restrict__ stat) {
  const int g = blockIdx.x;
  const int t = threadIdx.x;
  const float* base = c + (size_t)g * 4 * NN;
  float s = 0.f, ss = 0.f;
  for (int e = t; e < 4 * NN; e += 256) { float v = base[e]; s += v; ss += v * v; }
  #pragma unroll
  for (int off = 32; off > 0; off >>= 1) { s += __shfl_down(s, off); ss += __shfl_down(ss, off); }
  __shared__ float rs[4], rss[4];
  if ((t & 63) == 0) { rs[t >> 6] = s; rss[t >> 6] = ss; }
  __syncthreads();
  if (t == 0) {
    float S = rs[0] + rs[1] + rs[2] + rs[3];
    float SS = rss[0] + rss[1] + rss[2] + rss[3];
    float mu = S / (4.f * NN);
    float var = SS / (4.f * NN) - mu * mu;
    stat[g * 2] = mu;
    stat[g * 2 + 1] = rsqrtf(var + 1e-5f);
  }
}

// ---------------- Kuramoto step: GN + tangent projection + renorm + frag ----------------
__global__ void kur_update(const float* __restrict__ cb, const float* __restrict__ stat,
                           const float* __restrict__ gng, const float* __restrict__ gnb,
                           float* __restrict__ x4, f16* __restrict__ frag) {
  const int id = blockIdx.x * 256 + threadIdx.x;
  const int g = id >> 9, n0 = (id & 511) << 3;
  const float mu = stat[g * 2], rstd = stat[g * 2 + 1];
  float cn[4][8], xo[4][8];
  #pragma unroll
  for (int o = 0; o < 4; ++o) {
    size_t base = (size_t)(g * 4 + o) * NN + n0;
    f4 c0 = *(const f4*)(cb + base), c1 = *(const f4*)(cb + base + 4);
    f4 p0 = *(const f4*)(x4 + base), p1 = *(const f4*)(x4 + base + 4);
    float gg = gng[g * 4 + o], bb = gnb[g * 4 + o];
    cn[o][0]=(c0.x-mu)*rstd*gg+bb; cn[o][1]=(c0.y-mu)*rstd*gg+bb;
    cn[o][2]=(c0.z-mu)*rstd*gg+bb; cn[o][3]=(c0.w-mu)*rstd*gg+bb;
    cn[o][4]=(c1.x-mu)*rstd*gg+bb; cn[o][5]=(c1.y-mu)*rstd*gg+bb;
    cn[o][6]=(c1.z-mu)*rstd*gg+bb; cn[o][7]=(c1.w-mu)*rstd*gg+bb;
    xo[o][0]=p0.x; xo[o][1]=p0.y; xo[o][2]=p0.z; xo[o][3]=p0.w;
    xo[o][4]=p1.x; xo[o][5]=p1.y; xo[o][6]=p1.z; xo[o][7]=p1.w;
  }
  #pragma unroll
  for (int j = 0; j < 8; ++j) {
    float inner = cn[0][j]*xo[0][j] + cn[1][j]*xo[1][j] + cn[2][j]*xo[2][j] + cn[3][j]*xo[3][j];
    float ssq = 0.f;
    float xn[4];
    #pragma unroll
    for (int o = 0; o < 4; ++o) {
      xn[o] = xo[o][j] + (cn[o][j] - inner * xo[o][j]);
      ssq += xn[o] * xn[o];
    }
    float inv = 1.f / (sqrtf(ssq) + 1e-6f);
    #pragma unroll
    for (int o = 0; o < 4; ++o) cn[o][j] = xn[o] * inv;
  }
  #pragma unroll
  for (int o = 0; o < 4; ++o) {
    size_t base = (size_t)(g * 4 + o) * NN + n0;
    f4 a; a.x=cn[o][0]; a.y=cn[o][1]; a.z=cn[o][2]; a.w=cn[o][3];
    f4 b; b.x=cn[o][4]; b.y=cn[o][5]; b.z=cn[o][6]; b.w=cn[o][7];
    *(f4*)(x4 + base) = a; *(f4*)(x4 + base + 4) = b;
    f16x8 fr;
    #pragma unroll
    for (int j = 0; j < 8; ++j) fr[j] = (f16)cn[o][j];
    *(f16x8*)(frag + frag_off(8, g * 4 + o, n0)) = fr;
  }
}

// ---------------- head: logits[n,k] = sum_o xs[o,n]*out_w[k,o] + out_b[k] ----------------
__global__ void head(const float* __restrict__ xs, const float* __restrict__ ow,
                     const float* __restrict__ ob, float* __restrict__ out) {
  __shared__ float w[512];
  const int t = threadIdx.x;
  for (int e = t; e < 512; e += 256) w[e] = ow[e];
  __syncthreads();
  int n = blockIdx.x * 256 + t;
  float a0 = ob[0], a1 = ob[1], a2 = ob[2], a3 = ob[3];
  for (int o = 0; o < 128; ++o) {
    float v = xs[(size_t)o * NN + n];
    a0 += w[o] * v; a1 += w[128 + o] * v; a2 += w[256 + o] * v; a3 += w[384 + o] * v;
  }
  f4 r; r.x = a0; r.y = a1; r.z = a2; r.w = a3;
  ((f4*)out)[n] = r;
}

extern "C" void kernel_launch(void* const* d_in, const int* in_sizes, int n_in,
                              void* d_out, int out_size, void* d_ws, size_t ws_size,
                              hipStream_t stream) {
  const float* x      = (const float*)d_in[0];
  const float* adj    = (const float*)d_in[1];
  const float* mc_w0  = (const float*)d_in[2];
  const float* mc_b0  = (const float*)d_in[3];
  const float* mc_w1  = (const float*)d_in[4];
  const float* mc_b1  = (const float*)d_in[5];
  const float* mc_w2  = (const float*)d_in[6];
  const float* mc_b2  = (const float*)d_in[7];
  const float* mc_w3  = (const float*)d_in[8];
  const float* mc_b3  = (const float*)d_in[9];
  const float* proj_w = (const float*)d_in[10];
  const float* proj_b = (const float*)d_in[11];
  const float* pat_w  = (const float*)d_in[12];
  const float* pat_b  = (const float*)d_in[13];
  const float* kur_wc = (const float*)d_in[14];
  const float* kur_bc = (const float*)d_in[15];
  const float* kur_wy = (const float*)d_in[16];
  const float* kur_by = (const float*)d_in[17];
  const float* gn_g   = (const float*)d_in[18];
  const float* gn_b   = (const float*)d_in[19];
  const float* ro_w1  = (const float*)d_in[20];
  const float* ro_b1  = (const float*)d_in[21];
  const float* ro_w2  = (const float*)d_in[22];
  const float* ro_b2  = (const float*)d_in[23];
  const float* out_w  = (const float*)d_in[24];
  const float* out_b  = (const float*)d_in[25];
  float* out = (float*)d_out;
  float* Wf = (float*)d_ws;

  // ---- workspace layout (float offsets); total ~64.5 MiB ----
  f16*   adj16 = (f16*)d_ws;                    // 32 MB
  float* region = Wf + 8388608;                 // 8 MB multi-use
  float* cspart = region;                       //   colsum partials (2 MB)
  float* ybcn   = region;                       //   [256][N] (4 MB)
  float* ybuf   = region + 1048576;             //   y (2 MB)
  float* x0     = region;                       //   (2 MB, post-GST)
  float* part   = region;                       //   adjgemm partials (8 MB)
  f16*   fragA  = (f16*)(Wf + 10485760);        // 0.5 MB (F=64 rhs)
  f16*   fragB  = (f16*)(Wf + 10616832);        // 1 MB (F=128 rhs)
  float* xT     = Wf + 10878976;                // 1 MB
  float* A1     = Wf + 11141120;                // 1 MB (A3, mag alias)
  float* A2     = Wf + 11403264;                // 1 MB
  float* A4     = Wf + 11665408;                // 1 MB
  float* s1cat  = Wf + 11927552;                // 2 MB (B4, xst alias)
  float* B1     = Wf + 12451840;                // 2 MB
  float* B2     = Wf + 12976128;                // 2 MB
  float* gstf   = Wf + 13500416;                // 7 MB [448][N]
  float* cy     = Wf + 15335424;                // 2 MB
  float* x4     = Wf + 15859712;                // 2 MB
  float* cbuf   = Wf + 16384000;                // 2 MB (vbuf alias)
  float* deg    = Wf + 16908288;                // 4096
  float* gnst   = Wf + 16912384;                // 64
  float* magb   = A1;
  float* xst    = s1cat;

  dim3 b256(256);

  // 1. adj -> fp16 fragments + degree
  convert_cs<<<dim3(128, 2), b256, 0, stream>>>(adj, adj16, cspart);
  colsum_fin<<<dim3(16), b256, 0, stream>>>(cspart, deg);

  // 2. control pattern y and control term cy (uses region; done before GST partials)
  multiconv<<<dim3(256), b256, 0, stream>>>(x, mc_w0, mc_b0, mc_w1, mc_b1,
                                            mc_w2, mc_b2, mc_w3, mc_b3, ybcn);
  matmul128<<<dim3(64), b256, 0, stream>>>(proj_w, proj_b, ybcn, 256, nullptr, ybuf, 0, 0);
  matmul128<<<dim3(64), b256, 0, stream>>>(kur_wy, kur_by, ybuf, 128, nullptr, cy, 0, 0);

  // 3. x -> xT + gst coef0 + us0 frag
  transpose_x<<<dim3(64), b256, 0, stream>>>(x, deg, xT, gstf, fragA);

  // 4. GST first order (F=64, KZ=8)
  adjmm16<64, 8><<<dim3(512), b256, 0, stream>>>(adj16, fragA, part);
  reduce_P<<<dim3(128), b256, 0, stream>>>(part, xT, A1, fragA, deg, 64, 8);
  adjmm16<64, 8><<<dim3(512), b256, 0, stream>>>(adj16, fragA, part);
  reduce_P<<<dim3(128), b256, 0, stream>>>(part, A1, A2, fragA, deg, 64, 8);
  scatter_abs<<<dim3(128), b256, 0, stream>>>(xT, A1, gstf + 1 * NN, s1cat, fragB, 0, deg);
  scatter_abs<<<dim3(128), b256, 0, stream>>>(A1, A2, gstf + 2 * NN, s1cat + (size_t)64 * NN, fragB, 64, deg);
  adjmm16<64, 8><<<dim3(512), b256, 0, stream>>>(adj16, fragA, part);
  reduce_P<<<dim3(128), b256, 0, stream>>>(part, A2, A1, fragA, deg, 64, 8);   // A3 -> A1
  adjmm16<64, 8><<<dim3(512), b256, 0, stream>>>(adj16, fragA, part);
  reduce_P<<<dim3(128), b256, 0, stream>>>(part, A1, A4, nullptr, deg, 64, 8); // A4
  scatter_abs<<<dim3(128), b256, 0, stream>>>(A2, A4, gstf + 3 * NN, nullptr, nullptr, 0, deg);

  // 5. GST second order, batched [s1_0 | s1_1] (F=128, KZ=4)
  adjmm16<128, 4><<<dim3(512), b256, 0, stream>>>(adj16, fragB, part);
  reduce_P<<<dim3(256), b256, 0, stream>>>(part, s1cat, B1, fragB, deg, 128, 4);
  adjmm16<128, 4><<<dim3(512), b256, 0, stream>>>(adj16, fragB, part);
  reduce_P<<<dim3(256), b256, 0, stream>>>(part, B1, B2, fragB, deg, 128, 4);
  scatter_abs<<<dim3(128), b256, 0, stream>>>(B1, B2, gstf + 4 * NN, nullptr, nullptr, 0, deg);
  adjmm16<128, 4><<<dim3(512), b256, 0, stream>>>(adj16, fragB, part);
  reduce_P<<<dim3(256), b256, 0, stream>>>(part, B2, B1, fragB, deg, 128, 4);   // B3 -> B1
  adjmm16<128, 4><<<dim3(512), b256, 0, stream>>>(adj16, fragB, part);
  reduce_P<<<dim3(256), b256, 0, stream>>>(part, B1, s1cat, nullptr, deg, 128, 4); // B4 -> s1cat
  scatter_abs<<<dim3(128), b256, 0, stream>>>(B2, s1cat, gstf + 5 * NN, nullptr, nullptr, 0, deg);
  scatter_abs<<<dim3(128), b256, 0, stream>>>(B2 + (size_t)64 * NN, s1cat + (size_t)64 * NN,
                                              gstf + 6 * NN, nullptr, nullptr, 0, deg);

  // 6. x0 = pat_w @ gst + pat_b; oscillator init (emits Kuramoto rhs frag)
  matmul128<<<dim3(64), b256, 0, stream>>>(pat_w, pat_b, gstf, 448, nullptr, x0, 0, 0);
  norm_init<<<dim3(64), b256, 0, stream>>>(x0, x4, fragB);

  // 7. Kuramoto dynamics
  for (int q = 0; q < 8; ++q) {
    adjmm16<128, 4><<<dim3(512), b256, 0, stream>>>(adj16, fragB, part);
    matmul128<<<dim3(64), b256, 0, stream>>>(kur_wc, kur_bc, part, 128, cy, cbuf, 4, 0);
    gn_stats<<<dim3(32), b256, 0, stream>>>(cbuf, gnst);
    kur_update<<<dim3(64), b256, 0, stream>>>(cbuf, gnst, gn_g, gn_b, x4, fragB);
  }

  // 8. readout + head (mag fused into ro_w1 matmul)
  matmul128<<<dim3(64), b256, 0, stream>>>(ro_w1, ro_b1, x4, 128, nullptr, magb, 0, 1);
  matmul128<<<dim3(64), b256, 0, stream>>>(ro_w2, ro_b2, magb, 32, nullptr, xst, 0, 0);
  head<<<dim3(16), b256, 0, stream>>>(xst, out_w, out_b, out);
}